// Round 11
// baseline (1830.019 us; speedup 1.0000x reference)
//
#include <hip/hip_runtime.h>
#include <hip/hip_bf16.h>

#define U_CNT 50000
#define I_CNT 25000
#define D_DIM 64
#define N_CNT 75000
#define E_CNT 2000000
#define B_CNT 4096
#define BIN_ROWS 64
#define NBINS ((N_CNT + BIN_ROWS - 1) / BIN_ROWS)   // 1172
#define BIN_CAP 1984                                 // mean 1706, sd 41 -> +6.7 sigma
#define ROFF_SHIFT 17
#define CHUNK 16384
#define SCAT_T 1024
#define EPT (CHUNK / SCAT_T)                         // 16
#define NCHUNK ((E_CNT + CHUNK - 1) / CHUNK)         // 123
#define CUR_STRIDE 16                                // 1 cursor per 64B line

// ---------------------------------------------------------------------------
// needed-row bitmap for the sparse layer-3 pass
// ---------------------------------------------------------------------------
__global__ void mark_kernel(const int* __restrict__ users, const int* __restrict__ items,
                            unsigned int* __restrict__ bitmap) {
    const int i = blockIdx.x * blockDim.x + threadIdx.x;
    if (i < B_CNT) {
        const int r = users[i];
        atomicOr(&bitmap[r >> 5], 1u << (r & 31));
    } else if (i < 2 * B_CNT) {
        const int r = U_CNT + items[i - B_CNT];
        atomicOr(&bitmap[r >> 5], 1u << (r & 31));
    }
}

// ---------------------------------------------------------------------------
// Phase A: block-aggregated bin scatter (round-9 structure, 64-row bins).
// ---------------------------------------------------------------------------
__global__ void bin_scatter_agg(const int* __restrict__ row, const int* __restrict__ col,
                                const float* __restrict__ vals, int* __restrict__ cursor,
                                int2* __restrict__ bins) {
    __shared__ int hist[NBINS];
    __shared__ int base[NBINS];
    const int tid = threadIdx.x;
    const int e0 = blockIdx.x * CHUNK;

    int   r[EPT];
    int   c[EPT];
    float v[EPT];
    #pragma unroll
    for (int i = 0; i < EPT; ++i) {
        const int e = e0 + tid + i * SCAT_T;
        const bool ok = (e < E_CNT);
        r[i] = ok ? row[e]  : -1;
        c[i] = ok ? col[e]  : 0;
        v[i] = ok ? vals[e] : 0.f;
    }

    for (int i = tid; i < NBINS; i += SCAT_T) hist[i] = 0;
    __syncthreads();
    #pragma unroll
    for (int i = 0; i < EPT; ++i)
        if (r[i] >= 0) atomicAdd(&hist[r[i] >> 6], 1);
    __syncthreads();
    const int rot = (int)((blockIdx.x * 131u) % NBINS);
    for (int i = tid; i < NBINS; i += SCAT_T) {
        int ii = i + rot; if (ii >= NBINS) ii -= NBINS;
        const int cnt = hist[ii];
        base[ii] = cnt ? atomicAdd(&cursor[ii * CUR_STRIDE], cnt) : 0;
    }
    __syncthreads();
    for (int i = tid; i < NBINS; i += SCAT_T) hist[i] = 0;  // reuse as local cursor
    __syncthreads();
    #pragma unroll
    for (int i = 0; i < EPT; ++i) {
        if (r[i] < 0) continue;
        const int b = r[i] >> 6;
        const int p = base[b] + atomicAdd(&hist[b], 1);
        if (p < BIN_CAP)
            bins[(size_t)b * BIN_CAP + p] =
                make_int2(((r[i] & (BIN_ROWS - 1)) << ROFF_SHIFT) | c[i],
                          __float_as_int(v[i]));
    }
}

// ---------------------------------------------------------------------------
// Bin-centric SpMM: one block per 64-row bin, unsorted records, LDS f32
// atomics (lane=dim -> consecutive addrs -> conflict-free).
//   MODE 0: layer1  x = concat(eu,ei) in place; y = l1; acc = emb + l1
//   MODE 1: layer2  y = G*x; acc += y
//   MODE 2: layer3 sparse: only rows marked in bitmap; y = G*x (marked rows)
// ---------------------------------------------------------------------------
template <int MODE>
__global__ __launch_bounds__(512)
void bin_spmm(const int2* __restrict__ bins, const int* __restrict__ cnt,
              const float* __restrict__ x, const float* __restrict__ eu,
              const float* __restrict__ ei, float* __restrict__ y,
              float* __restrict__ acc, const unsigned int* __restrict__ bitmap) {
    __shared__ float ysh[BIN_ROWS][D_DIM];     // 16 KB
    __shared__ unsigned int need[2];
    const int bin = blockIdx.x;
    const int tid = threadIdx.x;
    const int n = min(cnt[bin * CUR_STRIDE], BIN_CAP);

    if (MODE == 2) {
        if (tid < 2) need[tid] = bitmap[bin * 2 + tid];
        __syncthreads();
        if ((need[0] | need[1]) == 0) return;
    }
    for (int i = tid; i < BIN_ROWS * D_DIM / 4; i += 512)
        ((float4*)ysh)[i] = make_float4(0.f, 0.f, 0.f, 0.f);
    __syncthreads();

    const int lane = tid & 63;
    const int wv   = tid >> 6;                 // 0..7
    const size_t bbase = (size_t)bin * BIN_CAP;

    for (int k0 = wv * 64; k0 < n; k0 += 512) {
        const int k = k0 + lane;
        const int2 p = (k < n) ? bins[bbase + k] : make_int2(0, 0);
        const int m = min(64, n - k0);
        #pragma unroll 8
        for (int j = 0; j < m; ++j) {
            const int   meta = __shfl(p.x, j);
            const float v    = __int_as_float(__shfl(p.y, j));
            const int ro = meta >> ROFF_SHIFT;
            const int c  = meta & 0x1FFFF;
            if (MODE == 2) {
                if (!((need[ro >> 5] >> (ro & 31)) & 1u)) continue;  // wave-uniform
            }
            float xv;
            if (MODE == 0)
                xv = (c < U_CNT) ? eu[(size_t)c * D_DIM + lane]
                                 : ei[(size_t)(c - U_CNT) * D_DIM + lane];
            else
                xv = x[(size_t)c * D_DIM + lane];
            atomicAdd(&ysh[ro][lane], v * xv);
        }
    }
    __syncthreads();

    for (int row = wv; row < BIN_ROWS; row += 8) {
        const int r = bin * BIN_ROWS + row;
        if (r >= N_CNT) break;
        const float a = ysh[row][lane];
        if (MODE == 0) {
            const float e0 = (r < U_CNT) ? eu[(size_t)r * D_DIM + lane]
                                         : ei[(size_t)(r - U_CNT) * D_DIM + lane];
            y[(size_t)r * D_DIM + lane] = a;
            acc[(size_t)r * D_DIM + lane] = e0 + a;
        } else if (MODE == 1) {
            y[(size_t)r * D_DIM + lane] = a;
            acc[(size_t)r * D_DIM + lane] += a;
        } else {
            if ((need[row >> 5] >> (row & 31)) & 1u)
                y[(size_t)r * D_DIM + lane] = a;
        }
    }
}

// ---------------------------------------------------------------------------
// epilogue, one wave per batch element; all gathers precomputed (y3).
// ---------------------------------------------------------------------------
__global__ void final_kernel(const float* __restrict__ acc, const float* __restrict__ y3,
                             const float* __restrict__ w_user, const float* __restrict__ w_item,
                             const float* __restrict__ xij0, const float* __restrict__ xij1,
                             const int* __restrict__ users, const int* __restrict__ items,
                             const int* __restrict__ xij, float* __restrict__ out) {
    const int lane = threadIdx.x & 63;
    const int b = (blockIdx.x * blockDim.x + threadIdx.x) >> 6;
    if (b >= B_CNT) return;
    const int u  = users[b];
    const int it = items[b];
    const int ri = U_CNT + it;

    const float ue = (acc[(size_t)u  * D_DIM + lane] + y3[(size_t)u  * D_DIM + lane]) * 0.25f;
    const float ie = (acc[(size_t)ri * D_DIM + lane] + y3[(size_t)ri * D_DIM + lane]) * 0.25f;

    float pu = 0.f, pi = 0.f;
    const float* wu = w_user + lane * D_DIM;
    const float* wi = w_item + lane * D_DIM;
    #pragma unroll
    for (int k = 0; k < 64; ++k) {
        const float uk = __shfl(ue, k);
        const float ik = __shfl(ie, k);
        pu = fmaf(wu[k], uk, pu);
        pi = fmaf(wi[k], ik, pi);
    }

    float m = pu;
    for (int off = 32; off; off >>= 1) m = fmaxf(m, __shfl_xor(m, off));
    const float epu = __expf(pu - m);
    float s = epu;
    for (int off = 32; off; off >>= 1) s += __shfl_xor(s, off);
    const float soft = epu / s;

    const float sig = 1.f / (1.f + __expf(-pi));
    float prod = 0.5f * soft * sig;
    for (int off = 32; off; off >>= 1) prod += __shfl_xor(prod, off);

    if (lane == 0) {
        const float xe = xij[b] ? xij1[it] : xij0[it];
        const float sx = 1.f / (1.f + __expf(-xe));
        out[b] = prod + 0.5f * sx;
    }
}

// ---------------------------------------------------------------------------
extern "C" void kernel_launch(void* const* d_in, const int* in_sizes, int n_in,
                              void* d_out, int out_size, void* d_ws, size_t ws_size,
                              hipStream_t stream) {
    const float* emb_user  = (const float*)d_in[0];
    const float* emb_item  = (const float*)d_in[1];
    const float* xij0      = (const float*)d_in[2];
    const float* xij1      = (const float*)d_in[3];
    const float* w_user    = (const float*)d_in[4];
    const float* w_item    = (const float*)d_in[5];
    const float* edge_vals = (const float*)d_in[6];
    const int*   edge_row  = (const int*)d_in[7];
    const int*   edge_col  = (const int*)d_in[8];
    const int*   users     = (const int*)d_in[9];
    const int*   items     = (const int*)d_in[10];
    const int*   xij       = (const int*)d_in[11];
    float* out = (float*)d_out;

    // workspace carve-up (~76.3 MB), no aliasing:
    //   acc | bufA (y1, then y3) | bufB (y2) | bins | cursor | bitmap
    float*        acc    = (float*)d_ws;                          // N*D
    float*        bufA   = acc  + (size_t)N_CNT * D_DIM;          // N*D
    float*        bufB   = bufA + (size_t)N_CNT * D_DIM;          // N*D
    int2*         bins   = (int2*)(bufB + (size_t)N_CNT * D_DIM); // NBINS*BIN_CAP
    int*          cursor = (int*)(bins + (size_t)NBINS * BIN_CAP);// NBINS*16
    unsigned int* bitmap = (unsigned int*)(cursor + NBINS * CUR_STRIDE); // 2*NBINS

    hipMemsetAsync(cursor, 0, NBINS * CUR_STRIDE * sizeof(int), stream);
    hipMemsetAsync(bitmap, 0, 2 * NBINS * sizeof(unsigned int), stream);
    mark_kernel<<<dim3((2 * B_CNT + 255) / 256), dim3(256), 0, stream>>>(users, items, bitmap);
    bin_scatter_agg<<<dim3(NCHUNK), dim3(SCAT_T), 0, stream>>>(edge_row, edge_col,
                                                               edge_vals, cursor, bins);

    bin_spmm<0><<<dim3(NBINS), dim3(512), 0, stream>>>(bins, cursor, nullptr,
                                                       emb_user, emb_item,
                                                       bufA, acc, nullptr);
    bin_spmm<1><<<dim3(NBINS), dim3(512), 0, stream>>>(bins, cursor, bufA,
                                                       nullptr, nullptr,
                                                       bufB, acc, nullptr);
    bin_spmm<2><<<dim3(NBINS), dim3(512), 0, stream>>>(bins, cursor, bufB,
                                                       nullptr, nullptr,
                                                       bufA, nullptr, bitmap);

    final_kernel<<<dim3(B_CNT * 64 / 256), dim3(256), 0, stream>>>(acc, bufA,
                                                                   w_user, w_item,
                                                                   xij0, xij1,
                                                                   users, items, xij, out);
}

// Round 14
// 737.387 us; speedup vs baseline: 2.4818x; 2.4818x over previous
//
#include <hip/hip_runtime.h>
#include <hip/hip_cooperative_groups.h>
#include <hip/hip_bf16.h>

namespace cg = cooperative_groups;

#define U_CNT 50000
#define I_CNT 25000
#define D_DIM 64
#define N_CNT 75000
#define E_CNT 2000000
#define B_CNT 4096
#define BIN_ROWS 128
#define NBINS ((N_CNT + BIN_ROWS - 1) / BIN_ROWS)   // 586
#define BIN_CAP 4032                                 // bin max ~3600 (+10 sigma)
#define NTHREADS 512
#define MAXBLOCKS 768
// mega CSR-build slicing (independent of launched grid size)
#define SLICES 768
#define MSLICE ((E_CNT + SLICES - 1) / SLICES)       // 2605
// fallback (round-9) scatter params
#define FCHUNK 16384
#define FSCAT_T 1024
#define FEPT (FCHUNK / FSCAT_T)                      // 16
#define FNCHUNK ((E_CNT + FCHUNK - 1) / FCHUNK)      // 123
#define CUR_STRIDE 16

struct SmemA { int hist[NBINS]; int start[NBINS]; int scan[1024]; };
struct SmemB { unsigned short gidx[BIN_CAP]; int h2[BIN_ROWS]; int lscan[BIN_ROWS]; int cur[BIN_ROWS]; };
union Smem { SmemA a; SmemB b; };   // ~9.6 KB

// ---------------------------------------------------------------------------
// shared device helpers (round-7/9 proven)
// ---------------------------------------------------------------------------
__device__ __forceinline__ float row_gather(int s, int en, int lane,
                                            const int2* __restrict__ pk,
                                            const float* __restrict__ x) {
    float a = 0.f;
    for (int base = s; base < en; base += 64) {
        int k = base + lane;
        int2 p = (k < en) ? pk[k] : make_int2(0, 0);
        int m = min(64, en - base);
        #pragma unroll 4
        for (int j = 0; j < m; ++j) {
            int   c = __shfl(p.x, j);
            float v = __int_as_float(__shfl(p.y, j));
            a = fmaf(v, x[c * D_DIM + lane], a);
        }
    }
    return a;
}

__device__ __forceinline__ float4 gather4(int s, int en, int lane,
                                          const int2* __restrict__ pk,
                                          const float4* __restrict__ x4) {
    const int sub = lane >> 4;
    const int q   = lane & 15;
    float4 a = make_float4(0.f, 0.f, 0.f, 0.f);
    for (int base = s; base < en; base += 64) {
        const int k = base + lane;
        const int2 p = (k < en) ? pk[k] : make_int2(0, 0);
        const int m = min(64, en - base);
        #pragma unroll 8
        for (int j = 0; j < m; j += 4) {
            const int src = j + sub;
            int   c = __shfl(p.x, src);
            float v = __int_as_float(__shfl(p.y, src));
            if (src >= m) { c = 0; v = 0.f; }
            const float4 xv = x4[(size_t)c * (D_DIM / 4) + q];
            a.x = fmaf(v, xv.x, a.x);
            a.y = fmaf(v, xv.y, a.y);
            a.z = fmaf(v, xv.z, a.z);
            a.w = fmaf(v, xv.w, a.w);
        }
    }
    #pragma unroll
    for (int off = 16; off < 64; off <<= 1) {
        a.x += __shfl_xor(a.x, off);
        a.y += __shfl_xor(a.y, off);
        a.z += __shfl_xor(a.z, off);
        a.w += __shfl_xor(a.w, off);
    }
    return a;
}

__device__ __forceinline__ void spmm1_body(int r, int lane, const int* rowptr,
                                           const int2* __restrict__ pk,
                                           const float4* __restrict__ eu4,
                                           const float4* __restrict__ ei4,
                                           float4* y4, float4* acc4) {
    const int sub = lane >> 4;
    const int q   = lane & 15;
    const int s = rowptr[r], en = rowptr[r + 1];
    float4 a = make_float4(0.f, 0.f, 0.f, 0.f);
    for (int base = s; base < en; base += 64) {
        const int k = base + lane;
        const int2 p = (k < en) ? pk[k] : make_int2(0, 0);
        const int m = min(64, en - base);
        #pragma unroll 8
        for (int j = 0; j < m; j += 4) {
            const int src = j + sub;
            int   c = __shfl(p.x, src);
            float v = __int_as_float(__shfl(p.y, src));
            if (src >= m) { c = 0; v = 0.f; }
            const float4* xp = (c < U_CNT) ? (eu4 + (size_t)c * 16)
                                           : (ei4 + (size_t)(c - U_CNT) * 16);
            const float4 xv = xp[q];
            a.x = fmaf(v, xv.x, a.x);
            a.y = fmaf(v, xv.y, a.y);
            a.z = fmaf(v, xv.z, a.z);
            a.w = fmaf(v, xv.w, a.w);
        }
    }
    #pragma unroll
    for (int off = 16; off < 64; off <<= 1) {
        a.x += __shfl_xor(a.x, off);
        a.y += __shfl_xor(a.y, off);
        a.z += __shfl_xor(a.z, off);
        a.w += __shfl_xor(a.w, off);
    }
    if (sub == 0) {
        const float4 e0 = (r < U_CNT) ? eu4[(size_t)r * 16 + q]
                                      : ei4[(size_t)(r - U_CNT) * 16 + q];
        y4[(size_t)r * 16 + q] = a;
        acc4[(size_t)r * 16 + q] = make_float4(e0.x + a.x, e0.y + a.y,
                                               e0.z + a.z, e0.w + a.w);
    }
}

__device__ __forceinline__ void final_body(int b, int lane, const int* rowptr,
                                           const int2* __restrict__ pk,
                                           const float* l2, const float* acc,
                                           const float* w_user, const float* w_item,
                                           const float* xij0, const float* xij1,
                                           const int* users, const int* items,
                                           const int* xij, float* out) {
    const int u  = users[b];
    const int it = items[b];
    const int ri = U_CNT + it;

    const float l3u = row_gather(rowptr[u],  rowptr[u + 1],  lane, pk, l2);
    const float l3i = row_gather(rowptr[ri], rowptr[ri + 1], lane, pk, l2);
    const float ue = (acc[(size_t)u  * D_DIM + lane] + l3u) * 0.25f;
    const float ie = (acc[(size_t)ri * D_DIM + lane] + l3i) * 0.25f;

    float pu = 0.f, pi = 0.f;
    const float* wu = w_user + lane * D_DIM;
    const float* wi = w_item + lane * D_DIM;
    #pragma unroll
    for (int k = 0; k < 64; ++k) {
        const float uk = __shfl(ue, k);
        const float ik = __shfl(ie, k);
        pu = fmaf(wu[k], uk, pu);
        pi = fmaf(wi[k], ik, pi);
    }
    float m = pu;
    for (int off = 32; off; off >>= 1) m = fmaxf(m, __shfl_xor(m, off));
    const float epu = __expf(pu - m);
    float s = epu;
    for (int off = 32; off; off >>= 1) s += __shfl_xor(s, off);
    const float soft = epu / s;
    const float sig = 1.f / (1.f + __expf(-pi));
    float prod = 0.5f * soft * sig;
    for (int off = 32; off; off >>= 1) prod += __shfl_xor(prod, off);
    if (lane == 0) {
        const float xe = xij[b] ? xij1[it] : xij0[it];
        const float sx = 1.f / (1.f + __expf(-xe));
        out[b] = prod + 0.5f * sx;
    }
}

// ===========================================================================
// MEGA: whole pipeline, one cooperative dispatch, grid-stride phases.
// ===========================================================================
__global__ __launch_bounds__(NTHREADS, 6)
void mega(const int* __restrict__ erow, const int* __restrict__ ecol,
          const float* __restrict__ evals, const float* __restrict__ eu,
          const float* __restrict__ ei, const float* __restrict__ w_user,
          const float* __restrict__ w_item, const float* __restrict__ xij0,
          const float* __restrict__ xij1, const int* __restrict__ users,
          const int* __restrict__ items, const int* __restrict__ xij,
          float* __restrict__ out, float* __restrict__ acc,
          float* __restrict__ bufA, float* __restrict__ bufB,
          int2* __restrict__ pk, int* __restrict__ counts,
          int* __restrict__ totals, int* __restrict__ binstart,
          int* __restrict__ rowptr) {
    __shared__ Smem sm;
    cg::grid_group grid = cg::this_grid();
    const int tid  = threadIdx.x;
    const int bid  = blockIdx.x;
    const int nblk = gridDim.x;
    const int lane = tid & 63;
    const int wv   = tid >> 6;
    const int gw   = bid * (NTHREADS / 64) + wv;
    const int nwv  = nblk * (NTHREADS / 64);
    int2* bins = (int2*)bufB;     // alias: bins dead before phase-6 writes bufB

    // ---- phase 1: per-slice histogram -> counts[slice][bin]
    for (int sb = bid; sb < SLICES; sb += nblk) {
        __syncthreads();
        for (int i = tid; i < NBINS; i += NTHREADS) sm.a.hist[i] = 0;
        __syncthreads();
        const int e0 = sb * MSLICE, e1 = min(e0 + MSLICE, E_CNT);
        for (int e = e0 + tid; e < e1; e += NTHREADS)
            atomicAdd(&sm.a.hist[erow[e] >> 7], 1);
        __syncthreads();
        for (int i = tid; i < NBINS; i += NTHREADS)
            counts[sb * NBINS + i] = sm.a.hist[i];
    }
    grid.sync();

    // ---- phase 2: per-bin exclusive scan across slices (wave per bin)
    for (int bin = gw; bin < NBINS; bin += nwv) {
        int carry = 0;
        for (int b0 = 0; b0 < SLICES; b0 += 64) {
            const int v = counts[(b0 + lane) * NBINS + bin];
            int incl = v;
            #pragma unroll
            for (int d = 1; d < 64; d <<= 1) {
                int t = __shfl_up(incl, d);
                if (lane >= d) incl += t;
            }
            counts[(b0 + lane) * NBINS + bin] = carry + incl - v;
            carry += __shfl(incl, 63);
        }
        if (lane == 0) totals[bin] = carry;
    }
    grid.sync();

    // ---- phase 3: block-local scan of totals -> start; scatter slices
    {
        for (int i = tid; i < 1024; i += NTHREADS)
            sm.a.scan[i] = (i < NBINS) ? totals[i] : 0;
        __syncthreads();
        for (int off = 1; off < 1024; off <<= 1) {
            const int t0 = (tid >= off) ? sm.a.scan[tid - off] : 0;
            const int t1 = sm.a.scan[tid + NTHREADS - off];
            __syncthreads();
            sm.a.scan[tid] += t0;
            sm.a.scan[tid + NTHREADS] += t1;
            __syncthreads();
        }
        for (int i = tid; i < NBINS; i += NTHREADS) {
            const int st = sm.a.scan[i] - totals[i];          // exclusive
            sm.a.start[i] = st;
            if (bid == 0) binstart[i] = st;
        }
        for (int sb = bid; sb < SLICES; sb += nblk) {
            __syncthreads();
            for (int i = tid; i < NBINS; i += NTHREADS)
                sm.a.hist[i] = sm.a.start[i] + counts[sb * NBINS + i];
            __syncthreads();
            const int e0 = sb * MSLICE, e1 = min(e0 + MSLICE, E_CNT);
            for (int e = e0 + tid; e < e1; e += NTHREADS) {
                const int r = erow[e];
                const int p = atomicAdd(&sm.a.hist[r >> 7], 1);
                bins[p] = make_int2(((r & (BIN_ROWS - 1)) << 17) | ecol[e],
                                    __float_as_int(evals[e]));
            }
        }
    }
    grid.sync();

    // ---- phase 4: per-bin in-LDS counting sort -> pk + rowptr
    for (int bin = bid; bin < NBINS; bin += nblk) {
        __syncthreads();
        const int start = binstart[bin];
        const int n = min(totals[bin], BIN_CAP);
        if (tid < BIN_ROWS) { sm.b.h2[tid] = 0; sm.b.cur[tid] = 0; }
        __syncthreads();
        for (int k = tid; k < n; k += NTHREADS)
            atomicAdd(&sm.b.h2[bins[start + k].x >> 17], 1);
        __syncthreads();
        if (tid == 0) {
            int run = 0;
            for (int i = 0; i < BIN_ROWS; ++i) { sm.b.lscan[i] = run; run += sm.b.h2[i]; }
        }
        __syncthreads();
        if (tid < BIN_ROWS) {
            const int r = bin * BIN_ROWS + tid;
            if (r < N_CNT) rowptr[r] = start + sm.b.lscan[tid];
        }
        for (int k = tid; k < n; k += NTHREADS) {
            const int ro = bins[start + k].x >> 17;
            const int dst = sm.b.lscan[ro] + atomicAdd(&sm.b.cur[ro], 1);
            sm.b.gidx[dst] = (unsigned short)k;
        }
        __syncthreads();
        for (int k = tid; k < n; k += NTHREADS) {
            const int2 q = bins[start + sm.b.gidx[k]];
            pk[start + k] = make_int2(q.x & 0x1FFFF, q.y);
        }
    }
    if (bid == 0 && tid == 0) rowptr[N_CNT] = E_CNT;
    grid.sync();

    // ---- phase 5: spmm layer 1
    for (int r = gw; r < N_CNT; r += nwv)
        spmm1_body(r, lane, rowptr, pk, (const float4*)eu, (const float4*)ei,
                   (float4*)bufA, (float4*)acc);
    grid.sync();

    // ---- phase 6: spmm layer 2: bufB = G*bufA ; acc += bufB
    for (int r = gw; r < N_CNT; r += nwv) {
        const float4 a = gather4(rowptr[r], rowptr[r + 1], lane, pk,
                                 (const float4*)bufA);
        if ((lane >> 4) == 0) {
            const int q = lane & 15;
            ((float4*)bufB)[(size_t)r * 16 + q] = a;
            float4* acc4 = (float4*)acc;
            const float4 t = acc4[(size_t)r * 16 + q];
            acc4[(size_t)r * 16 + q] = make_float4(t.x + a.x, t.y + a.y,
                                                   t.z + a.z, t.w + a.w);
        }
    }
    grid.sync();

    // ---- phase 7: fused layer-3 + epilogue
    for (int b = gw; b < B_CNT; b += nwv)
        final_body(b, lane, rowptr, pk, bufB, acc, w_user, w_item,
                   xij0, xij1, users, items, xij, out);
}

// ===========================================================================
// FALLBACK: round-9 multi-kernel path (measured 310.8 us, passed)
// ===========================================================================
__global__ void f_scatter(const int* __restrict__ row, const int* __restrict__ col,
                          const float* __restrict__ vals, int* __restrict__ cursor,
                          int2* __restrict__ bins) {
    __shared__ int hist[NBINS];
    __shared__ int base[NBINS];
    const int tid = threadIdx.x;
    const int e0 = blockIdx.x * FCHUNK;
    int   r[FEPT]; int c[FEPT]; float v[FEPT];
    #pragma unroll
    for (int i = 0; i < FEPT; ++i) {
        const int e = e0 + tid + i * FSCAT_T;
        const bool ok = (e < E_CNT);
        r[i] = ok ? row[e] : -1;
        c[i] = ok ? col[e] : 0;
        v[i] = ok ? vals[e] : 0.f;
    }
    for (int i = tid; i < NBINS; i += FSCAT_T) hist[i] = 0;
    __syncthreads();
    #pragma unroll
    for (int i = 0; i < FEPT; ++i)
        if (r[i] >= 0) atomicAdd(&hist[r[i] >> 7], 1);
    __syncthreads();
    const int rot = (int)((blockIdx.x * 67u) % NBINS);
    for (int i = tid; i < NBINS; i += FSCAT_T) {
        int ii = i + rot; if (ii >= NBINS) ii -= NBINS;
        const int cnt = hist[ii];
        base[ii] = cnt ? atomicAdd(&cursor[ii * CUR_STRIDE], cnt) : 0;
    }
    __syncthreads();
    for (int i = tid; i < NBINS; i += FSCAT_T) hist[i] = 0;
    __syncthreads();
    #pragma unroll
    for (int i = 0; i < FEPT; ++i) {
        if (r[i] < 0) continue;
        const int b = r[i] >> 7;
        const int p = base[b] + atomicAdd(&hist[b], 1);
        if (p < BIN_CAP)
            bins[(size_t)b * BIN_CAP + p] =
                make_int2(((r[i] & (BIN_ROWS - 1)) << 17) | c[i], __float_as_int(v[i]));
    }
}

__global__ void f_scan(const int* __restrict__ cnt, int* __restrict__ binstart,
                       int* __restrict__ rowptr) {
    __shared__ int tmp[1024];
    int v = (threadIdx.x < NBINS) ? cnt[threadIdx.x * CUR_STRIDE] : 0;
    tmp[threadIdx.x] = v;
    __syncthreads();
    for (int off = 1; off < 1024; off <<= 1) {
        int t = (threadIdx.x >= off) ? tmp[threadIdx.x - off] : 0;
        __syncthreads();
        tmp[threadIdx.x] += t;
        __syncthreads();
    }
    if (threadIdx.x < NBINS) binstart[threadIdx.x] = tmp[threadIdx.x] - v;
    if (threadIdx.x == 0) rowptr[N_CNT] = E_CNT;
}

__global__ void f_sort(const int2* __restrict__ bins, const int* __restrict__ cnt,
                       const int* __restrict__ binstart, int* __restrict__ rowptr,
                       int2* __restrict__ pk) {
    __shared__ int2 rec[BIN_CAP];
    __shared__ unsigned short gidx[BIN_CAP];
    __shared__ int hist[BIN_ROWS];
    __shared__ int lscan[BIN_ROWS];
    __shared__ int cur[BIN_ROWS];
    const int bin = blockIdx.x;
    const int n = min(cnt[bin * CUR_STRIDE], BIN_CAP);
    const size_t base = (size_t)bin * BIN_CAP;
    const int start = binstart[bin];
    const int tid = threadIdx.x;
    if (tid < BIN_ROWS) { hist[tid] = 0; cur[tid] = 0; }
    __syncthreads();
    for (int k = tid; k < n; k += 256) {
        const int2 q = bins[base + k];
        rec[k] = q;
        atomicAdd(&hist[q.x >> 17], 1);
    }
    __syncthreads();
    if (tid == 0) {
        int run = 0;
        for (int i = 0; i < BIN_ROWS; ++i) { lscan[i] = run; run += hist[i]; }
    }
    __syncthreads();
    if (tid < BIN_ROWS) {
        const int r = bin * BIN_ROWS + tid;
        if (r < N_CNT) rowptr[r] = start + lscan[tid];
    }
    for (int k = tid; k < n; k += 256) {
        const int ro = rec[k].x >> 17;
        const int dst = lscan[ro] + atomicAdd(&cur[ro], 1);
        gidx[dst] = (unsigned short)k;
    }
    __syncthreads();
    for (int k = tid; k < n; k += 256) {
        const int2 q = rec[gidx[k]];
        pk[start + k] = make_int2(q.x & 0x1FFFF, q.y);
    }
}

__global__ void f_spmm1(const int* __restrict__ rowptr, const int2* __restrict__ pk,
                        const float4* __restrict__ eu4, const float4* __restrict__ ei4,
                        float4* __restrict__ y4, float4* __restrict__ acc4) {
    const int lane = threadIdx.x & 63;
    const int r = (blockIdx.x * blockDim.x + threadIdx.x) >> 6;
    if (r >= N_CNT) return;
    spmm1_body(r, lane, rowptr, pk, eu4, ei4, y4, acc4);
}

__global__ void f_spmm2(const int* __restrict__ rowptr, const int2* __restrict__ pk,
                        const float4* __restrict__ x4, float4* __restrict__ y4,
                        float4* __restrict__ acc4) {
    const int lane = threadIdx.x & 63;
    const int r = (blockIdx.x * blockDim.x + threadIdx.x) >> 6;
    if (r >= N_CNT) return;
    const float4 a = gather4(rowptr[r], rowptr[r + 1], lane, pk, x4);
    if ((lane >> 4) == 0) {
        const int q = lane & 15;
        y4[(size_t)r * 16 + q] = a;
        const float4 t = acc4[(size_t)r * 16 + q];
        acc4[(size_t)r * 16 + q] = make_float4(t.x + a.x, t.y + a.y,
                                               t.z + a.z, t.w + a.w);
    }
}

__global__ void f_final(const int* __restrict__ rowptr, const int2* __restrict__ pk,
                        const float* __restrict__ l2, const float* __restrict__ acc,
                        const float* __restrict__ w_user, const float* __restrict__ w_item,
                        const float* __restrict__ xij0, const float* __restrict__ xij1,
                        const int* __restrict__ users, const int* __restrict__ items,
                        const int* __restrict__ xij, float* __restrict__ out) {
    const int lane = threadIdx.x & 63;
    const int b = (blockIdx.x * blockDim.x + threadIdx.x) >> 6;
    if (b >= B_CNT) return;
    final_body(b, lane, rowptr, pk, l2, acc, w_user, w_item,
               xij0, xij1, users, items, xij, out);
}

// ---------------------------------------------------------------------------
extern "C" void kernel_launch(void* const* d_in, const int* in_sizes, int n_in,
                              void* d_out, int out_size, void* d_ws, size_t ws_size,
                              hipStream_t stream) {
    const float* eu     = (const float*)d_in[0];
    const float* ei     = (const float*)d_in[1];
    const float* xij0   = (const float*)d_in[2];
    const float* xij1   = (const float*)d_in[3];
    const float* w_user = (const float*)d_in[4];
    const float* w_item = (const float*)d_in[5];
    const float* evals  = (const float*)d_in[6];
    const int*   erow   = (const int*)d_in[7];
    const int*   ecol   = (const int*)d_in[8];
    const int*   users  = (const int*)d_in[9];
    const int*   items  = (const int*)d_in[10];
    const int*   xij    = (const int*)d_in[11];
    float* out = (float*)d_out;

    // workspace: acc | bufA | bufB(alias bins) | pk | counts | totals | binstart | rowptr | cursor
    float* acc      = (float*)d_ws;                            // N*D
    float* bufA     = acc  + (size_t)N_CNT * D_DIM;            // N*D
    float* bufB     = bufA + (size_t)N_CNT * D_DIM;            // N*D (bins alias)
    int2*  pk       = (int2*)(bufB + (size_t)N_CNT * D_DIM);   // E
    int*   counts   = (int*)(pk + (size_t)E_CNT);              // SLICES*NBINS
    int*   totals   = counts + SLICES * NBINS;                 // NBINS
    int*   binstart = totals + NBINS;                          // NBINS
    int*   rowptr   = binstart + NBINS;                        // N+1
    int*   cursor   = rowptr + (N_CNT + 1);                    // NBINS*16 (fallback)
    int2*  bins     = (int2*)bufB;

    // runtime gate for cooperative launch (host-side queries: capture-safe,
    // deterministic -> same path every call)
    int dev = 0;  hipGetDevice(&dev);
    int coop = 0; hipDeviceGetAttribute(&coop, hipDeviceAttributeCooperativeLaunch, dev);
    int ncu = 0;  hipDeviceGetAttribute(&ncu, hipDeviceAttributeMultiprocessorCount, dev);
    int occ = 0;  hipOccupancyMaxActiveBlocksPerMultiprocessor(&occ, mega, NTHREADS, 0);
    int nblk = (occ > 0 && ncu > 0) ? (occ * ncu) : 0;
    if (nblk > MAXBLOCKS) nblk = MAXBLOCKS;

    if (coop && nblk >= 256) {
        void* args[] = {
            (void*)&erow, (void*)&ecol, (void*)&evals, (void*)&eu, (void*)&ei,
            (void*)&w_user, (void*)&w_item, (void*)&xij0, (void*)&xij1,
            (void*)&users, (void*)&items, (void*)&xij, (void*)&out,
            (void*)&acc, (void*)&bufA, (void*)&bufB, (void*)&pk,
            (void*)&counts, (void*)&totals, (void*)&binstart, (void*)&rowptr
        };
        hipError_t e = hipLaunchCooperativeKernel(mega, dim3(nblk), dim3(NTHREADS),
                                                  args, 0, stream);
        if (e == hipSuccess) return;
    }

    // ---- fallback: round-9 multi-kernel path ----
    hipMemsetAsync(cursor, 0, NBINS * CUR_STRIDE * sizeof(int), stream);
    f_scatter<<<dim3(FNCHUNK), dim3(FSCAT_T), 0, stream>>>(erow, ecol, evals, cursor, bins);
    f_scan<<<dim3(1), dim3(1024), 0, stream>>>(cursor, binstart, rowptr);
    f_sort<<<dim3(NBINS), dim3(256), 0, stream>>>(bins, cursor, binstart, rowptr, pk);
    dim3 sgrid((N_CNT * 64 + 255) / 256);
    f_spmm1<<<sgrid, dim3(256), 0, stream>>>(rowptr, pk, (const float4*)eu,
                                             (const float4*)ei, (float4*)bufA,
                                             (float4*)acc);
    f_spmm2<<<sgrid, dim3(256), 0, stream>>>(rowptr, pk, (const float4*)bufA,
                                             (float4*)bufB, (float4*)acc);
    f_final<<<dim3(B_CNT * 64 / 256), dim3(256), 0, stream>>>(rowptr, pk, bufB, acc,
                                                              w_user, w_item, xij0, xij1,
                                                              users, items, xij, out);
}

// Round 16
// 308.316 us; speedup vs baseline: 5.9355x; 2.3917x over previous
//
#include <hip/hip_runtime.h>
#include <hip/hip_bf16.h>

#define U_CNT 50000
#define I_CNT 25000
#define D_DIM 64
#define N_CNT 75000
#define E_CNT 2000000
#define B_CNT 4096
#define BIN_ROWS 128
#define NBINS ((N_CNT + BIN_ROWS - 1) / BIN_ROWS)   // 586
#define BIN_CAP 4032                                 // avg 3413, max ~3600
#define CHUNK 16384
#define SCAT_T 1024
#define EPT (CHUNK / SCAT_T)                         // 16
#define NCHUNK ((E_CNT + CHUNK - 1) / CHUNK)         // 123
#define CUR_STRIDE 16                                // 1 cursor per 64B line

// ---------------------------------------------------------------------------
// Phase A: block-aggregated bin scatter (round-9, measured)
// ---------------------------------------------------------------------------
__global__ void bin_scatter_agg(const int* __restrict__ row, const int* __restrict__ col,
                                const float* __restrict__ vals, int* __restrict__ cursor,
                                int2* __restrict__ bins) {
    __shared__ int hist[NBINS];
    __shared__ int base[NBINS];
    const int tid = threadIdx.x;
    const int e0 = blockIdx.x * CHUNK;

    int   r[EPT];
    int   c[EPT];
    float v[EPT];
    #pragma unroll
    for (int i = 0; i < EPT; ++i) {
        const int e = e0 + tid + i * SCAT_T;
        const bool ok = (e < E_CNT);
        r[i] = ok ? row[e]  : -1;
        c[i] = ok ? col[e]  : 0;
        v[i] = ok ? vals[e] : 0.f;
    }

    for (int i = tid; i < NBINS; i += SCAT_T) hist[i] = 0;
    __syncthreads();
    #pragma unroll
    for (int i = 0; i < EPT; ++i)
        if (r[i] >= 0) atomicAdd(&hist[r[i] >> 7], 1);
    __syncthreads();
    const int rot = (int)((blockIdx.x * 67u) % NBINS);
    for (int i = tid; i < NBINS; i += SCAT_T) {
        int ii = i + rot; if (ii >= NBINS) ii -= NBINS;
        const int cnt = hist[ii];
        base[ii] = cnt ? atomicAdd(&cursor[ii * CUR_STRIDE], cnt) : 0;
    }
    __syncthreads();
    for (int i = tid; i < NBINS; i += SCAT_T) hist[i] = 0;  // reuse as local cursor
    __syncthreads();
    #pragma unroll
    for (int i = 0; i < EPT; ++i) {
        if (r[i] < 0) continue;
        const int b = r[i] >> 7;
        const int p = base[b] + atomicAdd(&hist[b], 1);
        if (p < BIN_CAP)
            bins[(size_t)b * BIN_CAP + p] =
                make_int2(((r[i] & (BIN_ROWS - 1)) << 17) | c[i], __float_as_int(v[i]));
    }
}

// ---------------------------------------------------------------------------
// Exclusive scan of 586 (padded) bin counts -> binstart. Single 1024 block.
// ---------------------------------------------------------------------------
__global__ void bin_scan(const int* __restrict__ cnt, int* __restrict__ binstart,
                         int* __restrict__ rowptr) {
    __shared__ int tmp[1024];
    int v = (threadIdx.x < NBINS) ? cnt[threadIdx.x * CUR_STRIDE] : 0;
    tmp[threadIdx.x] = v;
    __syncthreads();
    for (int off = 1; off < 1024; off <<= 1) {
        int t = (threadIdx.x >= off) ? tmp[threadIdx.x - off] : 0;
        __syncthreads();
        tmp[threadIdx.x] += t;
        __syncthreads();
    }
    if (threadIdx.x < NBINS) binstart[threadIdx.x] = tmp[threadIdx.x] - v;  // exclusive
    if (threadIdx.x == 0) rowptr[N_CNT] = E_CNT;
}

// ---------------------------------------------------------------------------
// Phase B: in-LDS counting sort per bin — 512 threads: halves per-block
// record-pass latency; LDS 42 KB -> 3 blocks/CU, 24 waves.
// ---------------------------------------------------------------------------
__global__ __launch_bounds__(512)
void bin_sort(const int2* __restrict__ bins, const int* __restrict__ cnt,
              const int* __restrict__ binstart, int* __restrict__ rowptr,
              int2* __restrict__ pk) {
    __shared__ int2 rec[BIN_CAP];
    __shared__ unsigned short gidx[BIN_CAP];
    __shared__ int hist[BIN_ROWS];
    __shared__ int lscan[BIN_ROWS];
    __shared__ int cur[BIN_ROWS];
    const int bin = blockIdx.x;
    const int n = min(cnt[bin * CUR_STRIDE], BIN_CAP);
    const size_t base = (size_t)bin * BIN_CAP;
    const int start = binstart[bin];
    const int tid = threadIdx.x;

    if (tid < BIN_ROWS) { hist[tid] = 0; cur[tid] = 0; }
    __syncthreads();
    for (int k = tid; k < n; k += 512) {
        const int2 q = bins[base + k];
        rec[k] = q;
        atomicAdd(&hist[q.x >> 17], 1);
    }
    __syncthreads();
    if (tid == 0) {
        int run = 0;
        for (int i = 0; i < BIN_ROWS; ++i) { lscan[i] = run; run += hist[i]; }
    }
    __syncthreads();
    if (tid < BIN_ROWS) {
        const int r = bin * BIN_ROWS + tid;
        if (r < N_CNT) rowptr[r] = start + lscan[tid];
    }
    for (int k = tid; k < n; k += 512) {
        const int ro = rec[k].x >> 17;
        const int dst = lscan[ro] + atomicAdd(&cur[ro], 1);
        gidx[dst] = (unsigned short)k;
    }
    __syncthreads();
    for (int k = tid; k < n; k += 512) {
        const int2 q = rec[gidx[k]];
        pk[start + k] = make_int2(q.x & 0x1FFFF, q.y);
    }
}

// ---------------------------------------------------------------------------
// float4 gather: 4 subgroups x 16 lanes (round-7/9 measured structure)
// ---------------------------------------------------------------------------
__device__ __forceinline__ float4 gather4(int s, int en, int lane,
                                          const int2* __restrict__ pk,
                                          const float4* __restrict__ x4) {
    const int sub = lane >> 4;
    const int q   = lane & 15;
    float4 a = make_float4(0.f, 0.f, 0.f, 0.f);
    for (int base = s; base < en; base += 64) {
        const int k = base + lane;
        const int2 p = (k < en) ? pk[k] : make_int2(0, 0);
        const int m = min(64, en - base);
        #pragma unroll 8
        for (int j = 0; j < m; j += 4) {
            const int src = j + sub;
            int   c = __shfl(p.x, src);
            float v = __int_as_float(__shfl(p.y, src));
            if (src >= m) { c = 0; v = 0.f; }
            const float4 xv = x4[(size_t)c * (D_DIM / 4) + q];
            a.x = fmaf(v, xv.x, a.x);
            a.y = fmaf(v, xv.y, a.y);
            a.z = fmaf(v, xv.z, a.z);
            a.w = fmaf(v, xv.w, a.w);
        }
    }
    #pragma unroll
    for (int off = 16; off < 64; off <<= 1) {
        a.x += __shfl_xor(a.x, off);
        a.y += __shfl_xor(a.y, off);
        a.z += __shfl_xor(a.z, off);
        a.w += __shfl_xor(a.w, off);
    }
    return a;
}

// layer 1: x = concat(emb_user, emb_item) read in place; acc = emb + l1; y = l1
__global__ void spmm_layer1(const int* __restrict__ rowptr, const int2* __restrict__ pk,
                            const float4* __restrict__ eu4, const float4* __restrict__ ei4,
                            float4* __restrict__ y4, float4* __restrict__ acc4) {
    const int lane = threadIdx.x & 63;
    const int r = (blockIdx.x * blockDim.x + threadIdx.x) >> 6;
    if (r >= N_CNT) return;
    const int sub = lane >> 4;
    const int q   = lane & 15;
    const int s = rowptr[r], en = rowptr[r + 1];
    float4 a = make_float4(0.f, 0.f, 0.f, 0.f);
    for (int base = s; base < en; base += 64) {
        const int k = base + lane;
        const int2 p = (k < en) ? pk[k] : make_int2(0, 0);
        const int m = min(64, en - base);
        #pragma unroll 8
        for (int j = 0; j < m; j += 4) {
            const int src = j + sub;
            int   c = __shfl(p.x, src);
            float v = __int_as_float(__shfl(p.y, src));
            if (src >= m) { c = 0; v = 0.f; }
            const float4* xp = (c < U_CNT) ? (eu4 + (size_t)c * 16)
                                           : (ei4 + (size_t)(c - U_CNT) * 16);
            const float4 xv = xp[q];
            a.x = fmaf(v, xv.x, a.x);
            a.y = fmaf(v, xv.y, a.y);
            a.z = fmaf(v, xv.z, a.z);
            a.w = fmaf(v, xv.w, a.w);
        }
    }
    #pragma unroll
    for (int off = 16; off < 64; off <<= 1) {
        a.x += __shfl_xor(a.x, off);
        a.y += __shfl_xor(a.y, off);
        a.z += __shfl_xor(a.z, off);
        a.w += __shfl_xor(a.w, off);
    }
    if (sub == 0) {
        const float4 e0 = (r < U_CNT) ? eu4[(size_t)r * 16 + q]
                                      : ei4[(size_t)(r - U_CNT) * 16 + q];
        y4[(size_t)r * 16 + q] = a;
        acc4[(size_t)r * 16 + q] = make_float4(e0.x + a.x, e0.y + a.y,
                                               e0.z + a.z, e0.w + a.w);
    }
}

// layer 2: y = G*x ; acc += y
__global__ void spmm_layer2(const int* __restrict__ rowptr, const int2* __restrict__ pk,
                            const float4* __restrict__ x4, float4* __restrict__ y4,
                            float4* __restrict__ acc4) {
    const int lane = threadIdx.x & 63;
    const int r = (blockIdx.x * blockDim.x + threadIdx.x) >> 6;
    if (r >= N_CNT) return;
    const float4 a = gather4(rowptr[r], rowptr[r + 1], lane, pk, x4);
    if ((lane >> 4) == 0) {
        const int q = lane & 15;
        y4[(size_t)r * 16 + q] = a;
        const float4 t = acc4[(size_t)r * 16 + q];
        acc4[(size_t)r * 16 + q] = make_float4(t.x + a.x, t.y + a.y,
                                               t.z + a.z, t.w + a.w);
    }
}

// ---------------------------------------------------------------------------
// epilogue: one wave per batch element; DUAL interleaved row gather (u and i
// rows in the same loop -> 2 independent loads in flight).
// ---------------------------------------------------------------------------
__global__ void final_kernel(const int* __restrict__ rowptr, const int2* __restrict__ pk,
                             const float* __restrict__ l2, const float* __restrict__ acc,
                             const float* __restrict__ w_user, const float* __restrict__ w_item,
                             const float* __restrict__ xij0, const float* __restrict__ xij1,
                             const int* __restrict__ users, const int* __restrict__ items,
                             const int* __restrict__ xij, float* __restrict__ out) {
    const int lane = threadIdx.x & 63;
    const int b = (blockIdx.x * blockDim.x + threadIdx.x) >> 6;
    if (b >= B_CNT) return;
    const int u  = users[b];
    const int it = items[b];
    const int ri = U_CNT + it;

    // dual gather: iterate the longer segment, interleave both rows
    const int su = rowptr[u],  eu_ = rowptr[u + 1],  nu = eu_ - su;
    const int si = rowptr[ri], ei_ = rowptr[ri + 1], ni = ei_ - si;
    float l3u = 0.f, l3i = 0.f;
    const int nmax = max(nu, ni);
    for (int base = 0; base < nmax; base += 64) {
        const int ku = su + base + lane;
        const int ki = si + base + lane;
        const int2 pu_ = (base + lane < nu) ? pk[ku] : make_int2(0, 0);
        const int2 pi_ = (base + lane < ni) ? pk[ki] : make_int2(0, 0);
        const int mm = min(64, nmax - base);
        #pragma unroll 4
        for (int j = 0; j < mm; ++j) {
            const int   cu = __shfl(pu_.x, j);
            const float vu = __int_as_float(__shfl(pu_.y, j));
            const int   ci = __shfl(pi_.x, j);
            const float vi = __int_as_float(__shfl(pi_.y, j));
            if (base + j < nu) l3u = fmaf(vu, l2[cu * D_DIM + lane], l3u);
            if (base + j < ni) l3i = fmaf(vi, l2[ci * D_DIM + lane], l3i);
        }
    }

    const float ue = (acc[(size_t)u  * D_DIM + lane] + l3u) * 0.25f;
    const float ie = (acc[(size_t)ri * D_DIM + lane] + l3i) * 0.25f;

    float pu = 0.f, pi = 0.f;
    const float* wu = w_user + lane * D_DIM;
    const float* wi = w_item + lane * D_DIM;
    #pragma unroll
    for (int k = 0; k < 64; ++k) {
        const float uk = __shfl(ue, k);
        const float ik = __shfl(ie, k);
        pu = fmaf(wu[k], uk, pu);
        pi = fmaf(wi[k], ik, pi);
    }

    float m = pu;
    for (int off = 32; off; off >>= 1) m = fmaxf(m, __shfl_xor(m, off));
    const float epu = __expf(pu - m);
    float s = epu;
    for (int off = 32; off; off >>= 1) s += __shfl_xor(s, off);
    const float soft = epu / s;

    const float sig = 1.f / (1.f + __expf(-pi));
    float prod = 0.5f * soft * sig;
    for (int off = 32; off; off >>= 1) prod += __shfl_xor(prod, off);

    if (lane == 0) {
        const float xe = xij[b] ? xij1[it] : xij0[it];
        const float sx = 1.f / (1.f + __expf(-xe));
        out[b] = prod + 0.5f * sx;
    }
}

// ---------------------------------------------------------------------------
extern "C" void kernel_launch(void* const* d_in, const int* in_sizes, int n_in,
                              void* d_out, int out_size, void* d_ws, size_t ws_size,
                              hipStream_t stream) {
    const float* emb_user  = (const float*)d_in[0];
    const float* emb_item  = (const float*)d_in[1];
    const float* xij0      = (const float*)d_in[2];
    const float* xij1      = (const float*)d_in[3];
    const float* w_user    = (const float*)d_in[4];
    const float* w_item    = (const float*)d_in[5];
    const float* edge_vals = (const float*)d_in[6];
    const int*   edge_row  = (const int*)d_in[7];
    const int*   edge_col  = (const int*)d_in[8];
    const int*   users     = (const int*)d_in[9];
    const int*   items     = (const int*)d_in[10];
    const int*   xij       = (const int*)d_in[11];
    float* out = (float*)d_out;

    // workspace carve-up (~74 MB). Aliases (stream-order-safe):
    //   bins (18.9MB) aliases bufB  — dead before spmm_layer2 writes bufB
    //   cursor (37.5KB, 64B-padded) aliases bufA — dead before spmm_layer1
    float* acc    = (float*)d_ws;                           // N*D
    float* bufA   = acc  + (size_t)N_CNT * D_DIM;           // N*D  (alias: cursor)
    float* bufB   = bufA + (size_t)N_CNT * D_DIM;           // N*D  (alias: bins)
    int2*  pk     = (int2*)(bufB + (size_t)N_CNT * D_DIM);  // E
    int*   rowptr = (int*)(pk + (size_t)E_CNT);             // N+1
    int*   bstart = rowptr + (N_CNT + 1);                   // NBINS
    int*   cursor = (int*)bufA;                             // NBINS*16 ints
    int2*  bins   = (int2*)bufB;                            // NBINS*BIN_CAP*8B

    dim3 blk(256);

    // --- CSR build: reg-staged bin scatter -> scan -> in-LDS sort ---
    hipMemsetAsync(cursor, 0, NBINS * CUR_STRIDE * sizeof(int), stream);
    bin_scatter_agg<<<dim3(NCHUNK), dim3(SCAT_T), 0, stream>>>(edge_row, edge_col,
                                                               edge_vals, cursor, bins);
    bin_scan<<<dim3(1), dim3(1024), 0, stream>>>(cursor, bstart, rowptr);
    bin_sort<<<dim3(NBINS), dim3(512), 0, stream>>>(bins, cursor, bstart, rowptr, pk);

    // --- 2 full SpMM layers (layer 3 fused into epilogue) ---
    dim3 sgrid((N_CNT * 64 + 255) / 256);   // one wave per row
    spmm_layer1<<<sgrid, blk, 0, stream>>>(rowptr, pk, (const float4*)emb_user,
                                           (const float4*)emb_item, (float4*)bufA,
                                           (float4*)acc);
    spmm_layer2<<<sgrid, blk, 0, stream>>>(rowptr, pk, (const float4*)bufA,
                                           (float4*)bufB, (float4*)acc);

    // --- fused layer-3 + epilogue ---
    final_kernel<<<dim3(B_CNT * 64 / 256), blk, 0, stream>>>(rowptr, pk, bufB, acc,
                                                             w_user, w_item, xij0, xij1,
                                                             users, items, xij, out);
}